// Round 1
// baseline (1692.678 us; speedup 1.0000x reference)
//
#include <hip/hip_runtime.h>

#define N_NODES 20000
#define E_ORIG  320000
#define E_TOT   340000
#define NUM_GRAPHS 64

// ---- monotone float<->uint mapping for atomicMax-based segment_max ----
__device__ __forceinline__ unsigned fkey(float f) {
  unsigned b = __float_as_uint(f);
  return (b & 0x80000000u) ? ~b : (b | 0x80000000u);
}
__device__ __forceinline__ float keyf(unsigned k) {
  unsigned b = (k & 0x80000000u) ? (k ^ 0x80000000u) : ~k;
  return __uint_as_float(b);
}

// ---- C[M,N] = A[M,K] @ B[K,N], fp32, row-major. BM=BN=64, BK=16, 4x4/thread.
__global__ __launch_bounds__(256) void sgemm64(
    const float* __restrict__ A, const float* __restrict__ B,
    float* __restrict__ C, int M, int K, int N)
{
  __shared__ float As[16][65];   // +1 pad breaks bank conflicts
  __shared__ float Bs[16][64];
  const int bm = blockIdx.y * 64;
  const int bn = blockIdx.x * 64;
  const int tid = threadIdx.x;
  const int tx = tid & 15;
  const int ty = tid >> 4;
  const int arow = tid >> 2;          // 0..63
  const int ak   = (tid & 3) << 2;    // 0,4,8,12
  const int bk   = tid >> 4;          // 0..15
  const int bno  = (tid & 15) << 2;   // 0..60
  float acc[4][4] = {};
  for (int k0 = 0; k0 < K; k0 += 16) {
    float4 av = make_float4(0.f, 0.f, 0.f, 0.f);
    if (bm + arow < M) av = *(const float4*)&A[(size_t)(bm + arow) * K + k0 + ak];
    As[ak + 0][arow] = av.x; As[ak + 1][arow] = av.y;
    As[ak + 2][arow] = av.z; As[ak + 3][arow] = av.w;
    float4 bv = *(const float4*)&B[(size_t)(k0 + bk) * N + bn + bno];
    *(float4*)&Bs[bk][bno] = bv;
    __syncthreads();
    #pragma unroll
    for (int kk = 0; kk < 16; kk++) {
      float ar[4], br[4];
      #pragma unroll
      for (int i = 0; i < 4; i++) ar[i] = As[kk][(ty << 2) + i];
      #pragma unroll
      for (int j = 0; j < 4; j++) br[j] = Bs[kk][(tx << 2) + j];
      #pragma unroll
      for (int i = 0; i < 4; i++)
        #pragma unroll
        for (int j = 0; j < 4; j++) acc[i][j] += ar[i] * br[j];
    }
    __syncthreads();
  }
  #pragma unroll
  for (int i = 0; i < 4; i++) {
    int row = bm + (ty << 2) + i;
    if (row < M)
      *(float4*)&C[(size_t)row * N + bn + (tx << 2)] =
          make_float4(acc[i][0], acc[i][1], acc[i][2], acc[i][3]);
  }
}

// ---- per (edge, head): logits = att . leaky_relu(xl[src]+xr[dst]); segment max
__global__ __launch_bounds__(256) void edge_logits(
    const float* __restrict__ xl, const float* __restrict__ xr,
    const float* __restrict__ att,
    const int* __restrict__ esrc, const int* __restrict__ edst,
    int H, int logH, unsigned* __restrict__ mkey, float* __restrict__ logits)
{
  int wid = blockIdx.x * 4 + (threadIdx.x >> 6);   // one wave per (e,h)
  int lane = threadIdx.x & 63;
  if (wid >= E_TOT * H) return;
  int e = wid >> logH;
  int h = wid & (H - 1);
  int src, dst;
  if (e < E_ORIG) { src = esrc[e]; dst = edst[e]; }
  else            { src = dst = e - E_ORIG; }       // self loop
  int W = H << 6;
  float a = xl[(size_t)src * W + (h << 6) + lane] +
            xr[(size_t)dst * W + (h << 6) + lane];
  a = a > 0.f ? a : 0.2f * a;                       // leaky_relu, slope 0.2
  float v = a * att[(h << 6) + lane];
  #pragma unroll
  for (int off = 32; off > 0; off >>= 1) v += __shfl_down(v, off);
  if (lane == 0) {
    logits[e * H + h] = v;
    atomicMax(&mkey[dst * H + h], fkey(v));
  }
}

// ---- per (edge, h, c): acc[dst] += exp(logit-m) * xl[src]; denom[dst,h] += w
__global__ __launch_bounds__(256) void edge_scatter(
    const float* __restrict__ xl, const float* __restrict__ logits,
    const unsigned* __restrict__ mkey,
    const int* __restrict__ esrc, const int* __restrict__ edst,
    int H, int logW, float* __restrict__ denom, float* __restrict__ acc)
{
  int g = blockIdx.x * 256 + threadIdx.x;
  int W = H << 6;
  if (g >= E_TOT * W) return;      // E_TOT*256 = 87M < 2^31
  int e = g >> logW;
  int t = g & (W - 1);
  int h = t >> 6;
  int src, dst;
  if (e < E_ORIG) { src = esrc[e]; dst = edst[e]; }
  else            { src = dst = e - E_ORIG; }
  float m = keyf(mkey[dst * H + h]);
  float w = __expf(logits[e * H + h] - m);
  if ((t & 63) == 0) atomicAdd(&denom[dst * H + h], w);
  atomicAdd(&acc[(size_t)dst * W + t], w * xl[(size_t)src * W + t]);
}

// ---- h_out = acc/denom + bias  (layers 0,1 -> feeds next layer)
__global__ __launch_bounds__(256) void normalize_k(
    const float* __restrict__ acc, const float* __restrict__ denom,
    const float* __restrict__ bias, int H, int logW, float* __restrict__ out)
{
  int g = blockIdx.x * 256 + threadIdx.x;
  int W = H << 6;
  if (g >= N_NODES * W) return;
  int n = g >> logW;
  int t = g & (W - 1);
  out[g] = acc[g] / denom[n * H + (t >> 6)] + bias[t];
}

// ---- layer 2 (H=1): normalize + global_add_pool fused
__global__ __launch_bounds__(256) void normalize_pool(
    const float* __restrict__ acc, const float* __restrict__ denom,
    const float* __restrict__ bias, const int* __restrict__ batch,
    float* __restrict__ pooled)
{
  int g = blockIdx.x * 256 + threadIdx.x;
  if (g >= N_NODES * 64) return;
  int n = g >> 6;
  int c = g & 63;
  float v = acc[g] / denom[n] + bias[c];
  atomicAdd(&pooled[batch[n] * 64 + c], v);
}

// ---- BN (eval) + fc: out[g, j] = bn(pooled[g]) @ fc_w + fc_b
__global__ __launch_bounds__(64) void bn_fc(
    const float* __restrict__ pooled, const float* __restrict__ gamma,
    const float* __restrict__ beta, const float* __restrict__ mean,
    const float* __restrict__ var, const float* __restrict__ fcw,
    const float* __restrict__ fcb, float* __restrict__ out)
{
  __shared__ float s[64];
  int g = blockIdx.x;
  int t = threadIdx.x;
  float p = pooled[g * 64 + t];
  s[t] = (p - mean[t]) * rsqrtf(var[t] + 1e-5f) * gamma[t] + beta[t];
  __syncthreads();
  if (t < 32) {
    float a = fcb[t];
    #pragma unroll
    for (int c = 0; c < 64; c++) a += s[c] * fcw[c * 32 + t];
    out[g * 32 + t] = a;
  }
}

extern "C" void kernel_launch(void* const* d_in, const int* in_sizes, int n_in,
                              void* d_out, int out_size, void* d_ws, size_t ws_size,
                              hipStream_t stream) {
  const float* x    = (const float*)d_in[0];
  const int*   ei   = (const int*)d_in[1];
  const int*   batch= (const int*)d_in[2];
  const float* Wl0  = (const float*)d_in[3];
  const float* Wr0  = (const float*)d_in[4];
  const float* att0 = (const float*)d_in[5];
  const float* b0   = (const float*)d_in[6];
  const float* Wl1  = (const float*)d_in[7];
  const float* Wr1  = (const float*)d_in[8];
  const float* att1 = (const float*)d_in[9];
  const float* b1   = (const float*)d_in[10];
  const float* Wl2  = (const float*)d_in[11];
  const float* Wr2  = (const float*)d_in[12];
  const float* att2 = (const float*)d_in[13];
  const float* b2   = (const float*)d_in[14];
  const float* bng  = (const float*)d_in[15];
  const float* bnb  = (const float*)d_in[16];
  const float* bnm  = (const float*)d_in[17];
  const float* bnv  = (const float*)d_in[18];
  const float* fcw  = (const float*)d_in[19];
  const float* fcb  = (const float*)d_in[20];
  float* out = (float*)d_out;

  const int* esrc = ei;
  const int* edst = ei + E_ORIG;

  // workspace layout (floats): xl | xr(=acc after logits) | hbuf | logits | mkey | denom | pooled
  float* ws     = (float*)d_ws;
  float* xl     = ws;
  float* xracc  = xl    + (size_t)N_NODES * 256;
  float* hbuf   = xracc + (size_t)N_NODES * 256;
  float* logits = hbuf  + (size_t)N_NODES * 256;
  unsigned* mkey= (unsigned*)(logits + (size_t)E_TOT * 4);
  float* denom  = (float*)(mkey + (size_t)N_NODES * 4);
  float* pooled = denom + (size_t)N_NODES * 4;

  dim3 blk(256);
  const int mrows = (N_NODES + 63) / 64;   // 313

  struct Layer {
    const float *in, *Wl, *Wr, *att, *bias; int K, H;
  } L[3] = {
    { x,    Wl0, Wr0, att0, b0, 128, 4 },
    { hbuf, Wl1, Wr1, att1, b1, 256, 4 },
    { hbuf, Wl2, Wr2, att2, b2, 256, 1 },
  };

  for (int l = 0; l < 3; l++) {
    const int H = L[l].H, W = H * 64;
    const int logH = (H == 4) ? 2 : 0;
    const int logW = (H == 4) ? 8 : 6;
    dim3 ggemm(W / 64, mrows);
    sgemm64<<<ggemm, blk, 0, stream>>>(L[l].in, L[l].Wl, xl,    N_NODES, L[l].K, W);
    sgemm64<<<ggemm, blk, 0, stream>>>(L[l].in, L[l].Wr, xracc, N_NODES, L[l].K, W);
    hipMemsetAsync(mkey,  0, (size_t)N_NODES * H * 4, stream);
    hipMemsetAsync(denom, 0, (size_t)N_NODES * H * 4, stream);
    int T = E_TOT * H;
    edge_logits<<<dim3((T + 3) / 4), blk, 0, stream>>>(
        xl, xracc, L[l].att, esrc, edst, H, logH, mkey, logits);
    // xr is dead now; reuse as the accumulator
    hipMemsetAsync(xracc, 0, (size_t)N_NODES * W * 4, stream);
    edge_scatter<<<dim3((E_TOT * W + 255) / 256), blk, 0, stream>>>(
        xl, logits, mkey, esrc, edst, H, logW, denom, xracc);
    if (l < 2) {
      normalize_k<<<dim3((N_NODES * W + 255) / 256), blk, 0, stream>>>(
          xracc, denom, L[l].bias, H, logW, hbuf);
    } else {
      hipMemsetAsync(pooled, 0, NUM_GRAPHS * 64 * 4, stream);
      normalize_pool<<<dim3((N_NODES * 64 + 255) / 256), blk, 0, stream>>>(
          xracc, denom, L[l].bias, batch, pooled);
    }
  }

  bn_fc<<<dim3(NUM_GRAPHS), dim3(64), 0, stream>>>(
      pooled, bng, bnb, bnm, bnv, fcw, fcb, out);
}

// Round 2
// 637.944 us; speedup vs baseline: 2.6533x; 2.6533x over previous
//
#include <hip/hip_runtime.h>
#include <math.h>

#define N_NODES 20000
#define E_ORIG  320000
#define E_TOT   340000
#define NUM_GRAPHS 64

// ============ CSR build (by destination) ============

__global__ __launch_bounds__(256) void deg_count(
    const int* __restrict__ edst, int* __restrict__ deg)
{
  int e = blockIdx.x * 256 + threadIdx.x;
  if (e >= E_TOT) return;
  int dst = (e < E_ORIG) ? edst[e] : e - E_ORIG;   // self loop
  atomicAdd(&deg[dst], 1);
}

// single-block exclusive scan over 20000 degrees -> rowptr[20001], cursor copy
__global__ __launch_bounds__(1024) void scan_rowptr(
    const int* __restrict__ deg, int* __restrict__ rowptr, int* __restrict__ cursor)
{
  __shared__ int part[1024];
  const int t = threadIdx.x;
  const int CH = (N_NODES + 1023) / 1024;   // 20
  int base = t * CH;
  int s = 0;
  for (int i = 0; i < CH; i++) {
    int idx = base + i;
    if (idx < N_NODES) s += deg[idx];
  }
  part[t] = s;
  __syncthreads();
  for (int off = 1; off < 1024; off <<= 1) {
    int v = (t >= off) ? part[t - off] : 0;
    __syncthreads();
    part[t] += v;
    __syncthreads();
  }
  int run = (t == 0) ? 0 : part[t - 1];
  for (int i = 0; i < CH; i++) {
    int idx = base + i;
    if (idx < N_NODES) {
      rowptr[idx] = run;
      cursor[idx] = run;
      run += deg[idx];
    }
  }
  if (t == 1023) rowptr[N_NODES] = part[1023];
}

__global__ __launch_bounds__(256) void csr_fill(
    const int* __restrict__ esrc, const int* __restrict__ edst,
    int* __restrict__ cursor, int* __restrict__ csr_src)
{
  int e = blockIdx.x * 256 + threadIdx.x;
  if (e >= E_TOT) return;
  int src, dst;
  if (e < E_ORIG) { src = esrc[e]; dst = edst[e]; }
  else            { src = dst = e - E_ORIG; }
  int pos = atomicAdd(&cursor[dst], 1);
  csr_src[pos] = src;
}

// ============ GEMM: C[M,N] = A[M,K] @ B[K,N] fp32, 64x64 tile ============

__global__ __launch_bounds__(256) void sgemm64(
    const float* __restrict__ A, const float* __restrict__ B,
    float* __restrict__ C, int M, int K, int N)
{
  __shared__ float As[16][65];
  __shared__ float Bs[16][64];
  const int bm = blockIdx.y * 64;
  const int bn = blockIdx.x * 64;
  const int tid = threadIdx.x;
  const int tx = tid & 15;
  const int ty = tid >> 4;
  const int arow = tid >> 2;
  const int ak   = (tid & 3) << 2;
  const int bk   = tid >> 4;
  const int bno  = (tid & 15) << 2;
  float acc[4][4] = {};
  for (int k0 = 0; k0 < K; k0 += 16) {
    float4 av = make_float4(0.f, 0.f, 0.f, 0.f);
    if (bm + arow < M) av = *(const float4*)&A[(size_t)(bm + arow) * K + k0 + ak];
    As[ak + 0][arow] = av.x; As[ak + 1][arow] = av.y;
    As[ak + 2][arow] = av.z; As[ak + 3][arow] = av.w;
    float4 bv = *(const float4*)&B[(size_t)(k0 + bk) * N + bn + bno];
    *(float4*)&Bs[bk][bno] = bv;
    __syncthreads();
    #pragma unroll
    for (int kk = 0; kk < 16; kk++) {
      float ar[4], br[4];
      #pragma unroll
      for (int i = 0; i < 4; i++) ar[i] = As[kk][(ty << 2) + i];
      #pragma unroll
      for (int j = 0; j < 4; j++) br[j] = Bs[kk][(tx << 2) + j];
      #pragma unroll
      for (int i = 0; i < 4; i++)
        #pragma unroll
        for (int j = 0; j < 4; j++) acc[i][j] += ar[i] * br[j];
    }
    __syncthreads();
  }
  #pragma unroll
  for (int i = 0; i < 4; i++) {
    int row = bm + (ty << 2) + i;
    if (row < M)
      *(float4*)&C[(size_t)row * N + bn + (tx << 2)] =
          make_float4(acc[i][0], acc[i][1], acc[i][2], acc[i][3]);
  }
}

// ============ fused GATv2 edge phase: online softmax, gather, no atomics ====
// H=4: one block per dst node, wave w = head w, lane = channel.
__global__ __launch_bounds__(256) void gat_gather_h4(
    const float* __restrict__ xl, const float* __restrict__ xr,
    const float* __restrict__ att, const float* __restrict__ bias,
    const int* __restrict__ rowptr, const int* __restrict__ csr_src,
    float* __restrict__ out)
{
  const int n = blockIdx.x;
  const int c = threadIdx.x;          // 0..255 = h*64+lane
  const float xrv  = xr[(size_t)n * 256 + c];
  const float attv = att[c];
  const int beg = rowptr[n], end = rowptr[n + 1];
  float m = -INFINITY, l = 0.f, acc = 0.f;
  for (int p = beg; p < end; p++) {
    int src = csr_src[p];
    float xlv = xl[(size_t)src * 256 + c];
    float a = xlv + xrv;
    a = a > 0.f ? a : 0.2f * a;
    float v = a * attv;
    #pragma unroll
    for (int off = 32; off > 0; off >>= 1) v += __shfl_xor(v, off);
    float mn = fmaxf(m, v);
    float scale = __expf(m - mn);     // first iter: exp(-inf)=0
    float w = __expf(v - mn);
    acc = acc * scale + w * xlv;
    l = l * scale + w;
    m = mn;
  }
  out[(size_t)n * 256 + c] = acc / l + bias[c];
}

// H=1 (layer 2): wave per node (4 nodes/block), fused global_add_pool.
__global__ __launch_bounds__(256) void gat_gather_h1_pool(
    const float* __restrict__ xl, const float* __restrict__ xr,
    const float* __restrict__ att, const float* __restrict__ bias,
    const int* __restrict__ rowptr, const int* __restrict__ csr_src,
    const int* __restrict__ batch, float* __restrict__ pooled)
{
  const int n = blockIdx.x * 4 + (threadIdx.x >> 6);
  if (n >= N_NODES) return;
  const int lane = threadIdx.x & 63;
  const float xrv  = xr[(size_t)n * 64 + lane];
  const float attv = att[lane];
  const int beg = rowptr[n], end = rowptr[n + 1];
  float m = -INFINITY, l = 0.f, acc = 0.f;
  for (int p = beg; p < end; p++) {
    int src = csr_src[p];
    float xlv = xl[(size_t)src * 64 + lane];
    float a = xlv + xrv;
    a = a > 0.f ? a : 0.2f * a;
    float v = a * attv;
    #pragma unroll
    for (int off = 32; off > 0; off >>= 1) v += __shfl_xor(v, off);
    float mn = fmaxf(m, v);
    float scale = __expf(m - mn);
    float w = __expf(v - mn);
    acc = acc * scale + w * xlv;
    l = l * scale + w;
    m = mn;
  }
  float val = acc / l + bias[lane];
  atomicAdd(&pooled[batch[n] * 64 + lane], val);
}

// ============ BN (eval) + fc ============
__global__ __launch_bounds__(64) void bn_fc(
    const float* __restrict__ pooled, const float* __restrict__ gamma,
    const float* __restrict__ beta, const float* __restrict__ mean,
    const float* __restrict__ var, const float* __restrict__ fcw,
    const float* __restrict__ fcb, float* __restrict__ out)
{
  __shared__ float s[64];
  int g = blockIdx.x;
  int t = threadIdx.x;
  float p = pooled[g * 64 + t];
  s[t] = (p - mean[t]) * rsqrtf(var[t] + 1e-5f) * gamma[t] + beta[t];
  __syncthreads();
  if (t < 32) {
    float a = fcb[t];
    #pragma unroll
    for (int c = 0; c < 64; c++) a += s[c] * fcw[c * 32 + t];
    out[g * 32 + t] = a;
  }
}

extern "C" void kernel_launch(void* const* d_in, const int* in_sizes, int n_in,
                              void* d_out, int out_size, void* d_ws, size_t ws_size,
                              hipStream_t stream) {
  const float* x    = (const float*)d_in[0];
  const int*   ei   = (const int*)d_in[1];
  const int*   batch= (const int*)d_in[2];
  const float* Wl0  = (const float*)d_in[3];
  const float* Wr0  = (const float*)d_in[4];
  const float* att0 = (const float*)d_in[5];
  const float* b0   = (const float*)d_in[6];
  const float* Wl1  = (const float*)d_in[7];
  const float* Wr1  = (const float*)d_in[8];
  const float* att1 = (const float*)d_in[9];
  const float* b1   = (const float*)d_in[10];
  const float* Wl2  = (const float*)d_in[11];
  const float* Wr2  = (const float*)d_in[12];
  const float* att2 = (const float*)d_in[13];
  const float* b2   = (const float*)d_in[14];
  const float* bng  = (const float*)d_in[15];
  const float* bnb  = (const float*)d_in[16];
  const float* bnm  = (const float*)d_in[17];
  const float* bnv  = (const float*)d_in[18];
  const float* fcw  = (const float*)d_in[19];
  const float* fcb  = (const float*)d_in[20];
  float* out = (float*)d_out;

  const int* esrc = ei;
  const int* edst = ei + E_ORIG;

  // workspace: xl | xr | hbuf (floats) | deg | rowptr | cursor | csr_src | pooled
  float* ws   = (float*)d_ws;
  float* xl   = ws;
  float* xr   = xl + (size_t)N_NODES * 256;
  float* hbuf = xr + (size_t)N_NODES * 256;
  int* deg    = (int*)(hbuf + (size_t)N_NODES * 256);
  int* rowptr = deg + N_NODES;
  int* cursor = rowptr + N_NODES + 1;
  int* csr_src= cursor + N_NODES;
  float* pooled = (float*)(csr_src + E_TOT);

  dim3 blk(256);
  const int mrows = (N_NODES + 63) / 64;   // 313
  const int eblk  = (E_TOT + 255) / 256;

  // ---- CSR build (reused by all 3 layers) ----
  hipMemsetAsync(deg, 0, N_NODES * 4, stream);
  deg_count<<<dim3(eblk), blk, 0, stream>>>(edst, deg);
  scan_rowptr<<<dim3(1), dim3(1024), 0, stream>>>(deg, rowptr, cursor);
  csr_fill<<<dim3(eblk), blk, 0, stream>>>(esrc, edst, cursor, csr_src);

  struct Layer {
    const float *in, *Wl, *Wr, *att, *bias; int K, H;
  } L[3] = {
    { x,    Wl0, Wr0, att0, b0, 128, 4 },
    { hbuf, Wl1, Wr1, att1, b1, 256, 4 },
    { hbuf, Wl2, Wr2, att2, b2, 256, 1 },
  };

  for (int l = 0; l < 3; l++) {
    const int H = L[l].H, W = H * 64;
    dim3 ggemm(W / 64, mrows);
    sgemm64<<<ggemm, blk, 0, stream>>>(L[l].in, L[l].Wl, xl, N_NODES, L[l].K, W);
    sgemm64<<<ggemm, blk, 0, stream>>>(L[l].in, L[l].Wr, xr, N_NODES, L[l].K, W);
    if (l < 2) {
      gat_gather_h4<<<dim3(N_NODES), blk, 0, stream>>>(
          xl, xr, L[l].att, L[l].bias, rowptr, csr_src, hbuf);
    } else {
      hipMemsetAsync(pooled, 0, NUM_GRAPHS * 64 * 4, stream);
      gat_gather_h1_pool<<<dim3(N_NODES / 4), blk, 0, stream>>>(
          xl, xr, L[l].att, L[l].bias, rowptr, csr_src, batch, pooled);
    }
  }

  bn_fc<<<dim3(NUM_GRAPHS), dim3(64), 0, stream>>>(
      pooled, bng, bnb, bnm, bnv, fcw, fcb, out);
}

// Round 3
// 516.607 us; speedup vs baseline: 3.2765x; 1.2349x over previous
//
#include <hip/hip_runtime.h>
#include <math.h>

#define N_NODES 20000
#define E_ORIG  320000
#define E_TOT   340000
#define NUM_GRAPHS 64

// ============ CSR build (by destination) ============

__global__ __launch_bounds__(256) void deg_count(
    const int* __restrict__ edst, int* __restrict__ deg)
{
  int e = blockIdx.x * 256 + threadIdx.x;
  if (e >= E_TOT) return;
  int dst = (e < E_ORIG) ? edst[e] : e - E_ORIG;   // self loop
  atomicAdd(&deg[dst], 1);
}

__global__ __launch_bounds__(1024) void scan_rowptr(
    const int* __restrict__ deg, int* __restrict__ rowptr, int* __restrict__ cursor)
{
  __shared__ int part[1024];
  const int t = threadIdx.x;
  const int CH = (N_NODES + 1023) / 1024;   // 20
  int base = t * CH;
  int s = 0;
  for (int i = 0; i < CH; i++) {
    int idx = base + i;
    if (idx < N_NODES) s += deg[idx];
  }
  part[t] = s;
  __syncthreads();
  for (int off = 1; off < 1024; off <<= 1) {
    int v = (t >= off) ? part[t - off] : 0;
    __syncthreads();
    part[t] += v;
    __syncthreads();
  }
  int run = (t == 0) ? 0 : part[t - 1];
  for (int i = 0; i < CH; i++) {
    int idx = base + i;
    if (idx < N_NODES) {
      rowptr[idx] = run;
      cursor[idx] = run;
      run += deg[idx];
    }
  }
  if (t == 1023) rowptr[N_NODES] = part[1023];
}

__global__ __launch_bounds__(256) void csr_fill(
    const int* __restrict__ esrc, const int* __restrict__ edst,
    int* __restrict__ cursor, int* __restrict__ csr_src)
{
  int e = blockIdx.x * 256 + threadIdx.x;
  if (e >= E_TOT) return;
  int src, dst;
  if (e < E_ORIG) { src = esrc[e]; dst = edst[e]; }
  else            { src = dst = e - E_ORIG; }
  int pos = atomicAdd(&cursor[dst], 1);
  csr_src[pos] = src;
}

// ============ GEMM: C[M,N] = A[M,K] @ B[K,N] fp32, 64x64 tile ============

__global__ __launch_bounds__(256) void sgemm64(
    const float* __restrict__ A, const float* __restrict__ B,
    float* __restrict__ C, int M, int K, int N)
{
  __shared__ float As[16][65];
  __shared__ float Bs[16][64];
  const int bm = blockIdx.y * 64;
  const int bn = blockIdx.x * 64;
  const int tid = threadIdx.x;
  const int tx = tid & 15;
  const int ty = tid >> 4;
  const int arow = tid >> 2;
  const int ak   = (tid & 3) << 2;
  const int bk   = tid >> 4;
  const int bno  = (tid & 15) << 2;
  float acc[4][4] = {};
  for (int k0 = 0; k0 < K; k0 += 16) {
    float4 av = make_float4(0.f, 0.f, 0.f, 0.f);
    if (bm + arow < M) av = *(const float4*)&A[(size_t)(bm + arow) * K + k0 + ak];
    As[ak + 0][arow] = av.x; As[ak + 1][arow] = av.y;
    As[ak + 2][arow] = av.z; As[ak + 3][arow] = av.w;
    float4 bv = *(const float4*)&B[(size_t)(k0 + bk) * N + bn + bno];
    *(float4*)&Bs[bk][bno] = bv;
    __syncthreads();
    #pragma unroll
    for (int kk = 0; kk < 16; kk++) {
      float ar[4], br[4];
      #pragma unroll
      for (int i = 0; i < 4; i++) ar[i] = As[kk][(ty << 2) + i];
      #pragma unroll
      for (int j = 0; j < 4; j++) br[j] = Bs[kk][(tx << 2) + j];
      #pragma unroll
      for (int i = 0; i < 4; i++)
        #pragma unroll
        for (int j = 0; j < 4; j++) acc[i][j] += ar[i] * br[j];
    }
    __syncthreads();
  }
  #pragma unroll
  for (int i = 0; i < 4; i++) {
    int row = bm + (ty << 2) + i;
    if (row < M)
      *(float4*)&C[(size_t)row * N + bn + (tx << 2)] =
          make_float4(acc[i][0], acc[i][1], acc[i][2], acc[i][3]);
  }
}

// ============ fused GATv2 edge phase, H=4 ============
// ONE wave per dst node, all 4 heads. Lane l holds channels 4l..4l+3
// (lanes 0-15 = head 0, 16-31 = head 1, ...). float4 loads; 4-step 16-lane
// butterfly per-head dot reduce; no-max online softmax (logits are O(1),
// exp cannot overflow; softmax is shift-invariant).
__global__ __launch_bounds__(256) void gat_gather_h4(
    const float* __restrict__ xl, const float* __restrict__ xr,
    const float* __restrict__ att, const float* __restrict__ bias,
    const int* __restrict__ rowptr, const int* __restrict__ csr_src,
    float* __restrict__ out)
{
  const int n = blockIdx.x * 4 + (threadIdx.x >> 6);
  const int lane = threadIdx.x & 63;
  const int c4 = lane << 2;                  // channel base 4l
  const float4 xrv  = *(const float4*)&xr[(size_t)n * 256 + c4];
  const float4 attv = *(const float4*)&att[c4];
  const int beg = rowptr[n], end = rowptr[n + 1];
  float4 acc = make_float4(0.f, 0.f, 0.f, 0.f);
  float lsum = 0.f;
  for (int p = beg; p < end; p++) {
    int src = csr_src[p];
    float4 xlv = *(const float4*)&xl[(size_t)src * 256 + c4];
    float4 a;
    a.x = xlv.x + xrv.x; a.y = xlv.y + xrv.y;
    a.z = xlv.z + xrv.z; a.w = xlv.w + xrv.w;
    a.x = fmaxf(a.x, 0.2f * a.x); a.y = fmaxf(a.y, 0.2f * a.y);
    a.z = fmaxf(a.z, 0.2f * a.z); a.w = fmaxf(a.w, 0.2f * a.w);
    float v = a.x * attv.x + a.y * attv.y + a.z * attv.z + a.w * attv.w;
    v += __shfl_xor(v, 1);
    v += __shfl_xor(v, 2);
    v += __shfl_xor(v, 4);
    v += __shfl_xor(v, 8);       // per-head logit, resident in that head's lanes
    float w = __expf(v);
    lsum += w;
    acc.x += w * xlv.x; acc.y += w * xlv.y;
    acc.z += w * xlv.z; acc.w += w * xlv.w;
  }
  const float4 bv = *(const float4*)&bias[c4];
  float inv = 1.f / lsum;
  float4 o;
  o.x = acc.x * inv + bv.x; o.y = acc.y * inv + bv.y;
  o.z = acc.z * inv + bv.z; o.w = acc.w * inv + bv.w;
  *(float4*)&out[(size_t)n * 256 + c4] = o;
}

// H=1 (layer 2): wave per node, lane = channel; no-max softmax; fused pool.
__global__ __launch_bounds__(256) void gat_gather_h1_pool(
    const float* __restrict__ xl, const float* __restrict__ xr,
    const float* __restrict__ att, const float* __restrict__ bias,
    const int* __restrict__ rowptr, const int* __restrict__ csr_src,
    const int* __restrict__ batch, float* __restrict__ pooled)
{
  const int n = blockIdx.x * 4 + (threadIdx.x >> 6);
  if (n >= N_NODES) return;
  const int lane = threadIdx.x & 63;
  const float xrv  = xr[(size_t)n * 64 + lane];
  const float attv = att[lane];
  const int beg = rowptr[n], end = rowptr[n + 1];
  float lsum = 0.f, acc = 0.f;
  for (int p = beg; p < end; p++) {
    int src = csr_src[p];
    float xlv = xl[(size_t)src * 64 + lane];
    float a = xlv + xrv;
    a = fmaxf(a, 0.2f * a);
    float v = a * attv;
    #pragma unroll
    for (int off = 32; off > 0; off >>= 1) v += __shfl_xor(v, off);
    float w = __expf(v);
    lsum += w;
    acc += w * xlv;
  }
  float val = acc / lsum + bias[lane];
  atomicAdd(&pooled[batch[n] * 64 + lane], val);
}

// ============ BN (eval) + fc ============
__global__ __launch_bounds__(64) void bn_fc(
    const float* __restrict__ pooled, const float* __restrict__ gamma,
    const float* __restrict__ beta, const float* __restrict__ mean,
    const float* __restrict__ var, const float* __restrict__ fcw,
    const float* __restrict__ fcb, float* __restrict__ out)
{
  __shared__ float s[64];
  int g = blockIdx.x;
  int t = threadIdx.x;
  float p = pooled[g * 64 + t];
  s[t] = (p - mean[t]) * rsqrtf(var[t] + 1e-5f) * gamma[t] + beta[t];
  __syncthreads();
  if (t < 32) {
    float a = fcb[t];
    #pragma unroll
    for (int c = 0; c < 64; c++) a += s[c] * fcw[c * 32 + t];
    out[g * 32 + t] = a;
  }
}

extern "C" void kernel_launch(void* const* d_in, const int* in_sizes, int n_in,
                              void* d_out, int out_size, void* d_ws, size_t ws_size,
                              hipStream_t stream) {
  const float* x    = (const float*)d_in[0];
  const int*   ei   = (const int*)d_in[1];
  const int*   batch= (const int*)d_in[2];
  const float* Wl0  = (const float*)d_in[3];
  const float* Wr0  = (const float*)d_in[4];
  const float* att0 = (const float*)d_in[5];
  const float* b0   = (const float*)d_in[6];
  const float* Wl1  = (const float*)d_in[7];
  const float* Wr1  = (const float*)d_in[8];
  const float* att1 = (const float*)d_in[9];
  const float* b1   = (const float*)d_in[10];
  const float* Wl2  = (const float*)d_in[11];
  const float* Wr2  = (const float*)d_in[12];
  const float* att2 = (const float*)d_in[13];
  const float* b2   = (const float*)d_in[14];
  const float* bng  = (const float*)d_in[15];
  const float* bnb  = (const float*)d_in[16];
  const float* bnm  = (const float*)d_in[17];
  const float* bnv  = (const float*)d_in[18];
  const float* fcw  = (const float*)d_in[19];
  const float* fcb  = (const float*)d_in[20];
  float* out = (float*)d_out;

  const int* esrc = ei;
  const int* edst = ei + E_ORIG;

  // workspace: xl | xr | hbuf (floats) | deg | rowptr | cursor | csr_src | pooled
  float* ws   = (float*)d_ws;
  float* xl   = ws;
  float* xr   = xl + (size_t)N_NODES * 256;
  float* hbuf = xr + (size_t)N_NODES * 256;
  int* deg    = (int*)(hbuf + (size_t)N_NODES * 256);
  int* rowptr = deg + N_NODES;
  int* cursor = rowptr + N_NODES + 1;
  int* csr_src= cursor + N_NODES;
  float* pooled = (float*)(csr_src + E_TOT);

  dim3 blk(256);
  const int mrows = (N_NODES + 63) / 64;   // 313
  const int eblk  = (E_TOT + 255) / 256;

  // ---- CSR build (reused by all 3 layers) ----
  hipMemsetAsync(deg, 0, N_NODES * 4, stream);
  deg_count<<<dim3(eblk), blk, 0, stream>>>(edst, deg);
  scan_rowptr<<<dim3(1), dim3(1024), 0, stream>>>(deg, rowptr, cursor);
  csr_fill<<<dim3(eblk), blk, 0, stream>>>(esrc, edst, cursor, csr_src);

  struct Layer {
    const float *in, *Wl, *Wr, *att, *bias; int K, H;
  } L[3] = {
    { x,    Wl0, Wr0, att0, b0, 128, 4 },
    { hbuf, Wl1, Wr1, att1, b1, 256, 4 },
    { hbuf, Wl2, Wr2, att2, b2, 256, 1 },
  };

  for (int l = 0; l < 3; l++) {
    const int H = L[l].H, W = H * 64;
    dim3 ggemm(W / 64, mrows);
    sgemm64<<<ggemm, blk, 0, stream>>>(L[l].in, L[l].Wl, xl, N_NODES, L[l].K, W);
    sgemm64<<<ggemm, blk, 0, stream>>>(L[l].in, L[l].Wr, xr, N_NODES, L[l].K, W);
    if (l < 2) {
      gat_gather_h4<<<dim3(N_NODES / 4), blk, 0, stream>>>(
          xl, xr, L[l].att, L[l].bias, rowptr, csr_src, hbuf);
    } else {
      hipMemsetAsync(pooled, 0, NUM_GRAPHS * 64 * 4, stream);
      gat_gather_h1_pool<<<dim3(N_NODES / 4), blk, 0, stream>>>(
          xl, xr, L[l].att, L[l].bias, rowptr, csr_src, batch, pooled);
    }
  }

  bn_fc<<<dim3(NUM_GRAPHS), dim3(64), 0, stream>>>(
      pooled, bng, bnb, bnm, bnv, fcw, fcb, out);
}

// Round 4
// 432.573 us; speedup vs baseline: 3.9130x; 1.1943x over previous
//
#include <hip/hip_runtime.h>
#include <math.h>

#define N_NODES 20000
#define E_ORIG  320000
#define E_TOT   340000
#define NUM_GRAPHS 64

typedef __attribute__((ext_vector_type(8))) short bf16x8;
typedef __attribute__((ext_vector_type(4))) float f32x4;

// fp32 -> bf16 RNE
__device__ __forceinline__ ushort f2bf(float x) {
  unsigned u = __float_as_uint(x);
  return (ushort)((u + 0x7fffu + ((u >> 16) & 1u)) >> 16);
}
// 4 consecutive bf16 -> float4 (8B load)
__device__ __forceinline__ float4 ld_bf16x4(const ushort* p) {
  ushort4 u = *(const ushort4*)p;
  float4 f;
  f.x = __uint_as_float((unsigned)u.x << 16);
  f.y = __uint_as_float((unsigned)u.y << 16);
  f.z = __uint_as_float((unsigned)u.z << 16);
  f.w = __uint_as_float((unsigned)u.w << 16);
  return f;
}
// async global->LDS, 16B per lane; lds ptr MUST be base + lane*16 in lane order
__device__ __forceinline__ void gl_lds16(const void* g, void* l) {
  __builtin_amdgcn_global_load_lds(
      (const __attribute__((address_space(1))) unsigned*)(uintptr_t)g,
      (__attribute__((address_space(3))) unsigned*)(uintptr_t)l, 16, 0, 0);
}

// ============ CSR build (by destination) ============

__global__ __launch_bounds__(256) void deg_count(
    const int* __restrict__ edst, int* __restrict__ deg)
{
  int e = blockIdx.x * 256 + threadIdx.x;
  if (e >= E_TOT) return;
  int dst = (e < E_ORIG) ? edst[e] : e - E_ORIG;
  atomicAdd(&deg[dst], 1);
}

__global__ __launch_bounds__(1024) void scan_rowptr(
    const int* __restrict__ deg, int* __restrict__ rowptr, int* __restrict__ cursor)
{
  __shared__ int part[1024];
  const int t = threadIdx.x;
  const int CH = (N_NODES + 1023) / 1024;
  int base = t * CH;
  int s = 0;
  for (int i = 0; i < CH; i++) {
    int idx = base + i;
    if (idx < N_NODES) s += deg[idx];
  }
  part[t] = s;
  __syncthreads();
  for (int off = 1; off < 1024; off <<= 1) {
    int v = (t >= off) ? part[t - off] : 0;
    __syncthreads();
    part[t] += v;
    __syncthreads();
  }
  int run = (t == 0) ? 0 : part[t - 1];
  for (int i = 0; i < CH; i++) {
    int idx = base + i;
    if (idx < N_NODES) {
      rowptr[idx] = run;
      cursor[idx] = run;
      run += deg[idx];
    }
  }
  if (t == 1023) rowptr[N_NODES] = part[1023];
}

__global__ __launch_bounds__(256) void csr_fill(
    const int* __restrict__ esrc, const int* __restrict__ edst,
    int* __restrict__ cursor, int* __restrict__ csr_src)
{
  int e = blockIdx.x * 256 + threadIdx.x;
  if (e >= E_TOT) return;
  int src, dst;
  if (e < E_ORIG) { src = esrc[e]; dst = edst[e]; }
  else            { src = dst = e - E_ORIG; }
  int pos = atomicAdd(&cursor[dst], 1);
  csr_src[pos] = src;
}

// ============ casts / weight packing ============

__global__ __launch_bounds__(256) void cast_bf16(
    const float* __restrict__ in, ushort* __restrict__ out, int n4)
{
  int i = (blockIdx.x * 256 + threadIdx.x) << 2;
  if (i >= n4) return;
  float4 v = *(const float4*)&in[i];
  ushort4 o;
  o.x = f2bf(v.x); o.y = f2bf(v.y); o.z = f2bf(v.z); o.w = f2bf(v.w);
  *(ushort4*)&out[i] = o;
}

// Bt[n][k] = (n<W ? Wl : Wr)[k][n%W], bf16.  N = 2W rows, K cols.
__global__ __launch_bounds__(256) void pack_wt(
    const float* __restrict__ Wl, const float* __restrict__ Wr,
    ushort* __restrict__ Bt, int K, int W)
{
  int idx = blockIdx.x * 256 + threadIdx.x;
  if (idx >= 2 * W * K) return;
  int n = idx / K, k = idx - n * K;
  float v = (n < W) ? Wl[(size_t)k * W + n] : Wr[(size_t)k * W + (n - W)];
  Bt[idx] = f2bf(v);
}

// ============ bf16 MFMA GEMM: C[M,N] = A[M,K] @ Bt[N,K]^T ============
// 128x128 block tile, 4 waves each 64x64 (4x4 16x16x32 MFMAs), BK=32,
// global_load_lds width-16 staging. M-edge clamped, K%32==0, N%128==0.
__global__ __launch_bounds__(256) void mfma_gemm_bf16(
    const ushort* __restrict__ A, const ushort* __restrict__ Bt,
    ushort* __restrict__ C, int M, int K, int N)
{
  __shared__ ushort As[128 * 32];
  __shared__ ushort Bs[128 * 32];
  const int m0 = blockIdx.x * 128;
  const int n0 = blockIdx.y * 128;
  const int tid = threadIdx.x;
  const int lane = tid & 63;
  const int w = tid >> 6;
  const int wm = (w >> 1) << 6;     // wave row origin in tile
  const int wn = (w & 1) << 6;      // wave col origin in tile
  const int quad = lane >> 4;
  const int l15 = lane & 15;

  f32x4 acc[4][4] = {};

  for (int k0 = 0; k0 < K; k0 += 32) {
    #pragma unroll
    for (int r = 0; r < 2; r++) {
      int c = (r << 8) + tid;            // chunk id 0..511
      int row = c >> 2;                  // tile row
      int col = (c & 3) << 3;            // element col in [0,32)
      int grow = m0 + row; if (grow >= M) grow = M - 1;
      gl_lds16(A  + (size_t)grow * K + k0 + col, (char*)As + c * 16);
      gl_lds16(Bt + (size_t)(n0 + row) * K + k0 + col, (char*)Bs + c * 16);
    }
    __syncthreads();
    bf16x8 af[4], bfr[4];
    #pragma unroll
    for (int i = 0; i < 4; i++)
      af[i]  = *(const bf16x8*)&As[(wm + (i << 4) + l15) * 32 + (quad << 3)];
    #pragma unroll
    for (int j = 0; j < 4; j++)
      bfr[j] = *(const bf16x8*)&Bs[(wn + (j << 4) + l15) * 32 + (quad << 3)];
    #pragma unroll
    for (int i = 0; i < 4; i++)
      #pragma unroll
      for (int j = 0; j < 4; j++)
        acc[i][j] = __builtin_amdgcn_mfma_f32_16x16x32_bf16(
            af[i], bfr[j], acc[i][j], 0, 0, 0);
    __syncthreads();
  }

  #pragma unroll
  for (int i = 0; i < 4; i++) {
    #pragma unroll
    for (int r = 0; r < 4; r++) {
      int grow = m0 + wm + (i << 4) + (quad << 2) + r;
      if (grow >= M) continue;
      #pragma unroll
      for (int j = 0; j < 4; j++) {
        int gcol = n0 + wn + (j << 4) + l15;
        C[(size_t)grow * N + gcol] = f2bf(acc[i][j][r]);
      }
    }
  }
}

// ============ GATv2 edge phase, H=4, bf16 in/out ============
// Cin rows: [xl(256) | xr(256)]. One wave per node; lane l = channels 4l..4l+3.
__global__ __launch_bounds__(256) void gat_gather_h4(
    const ushort* __restrict__ Cin, const float* __restrict__ att,
    const float* __restrict__ bias, const int* __restrict__ rowptr,
    const int* __restrict__ csr_src, ushort* __restrict__ hout)
{
  const int n = blockIdx.x * 4 + (threadIdx.x >> 6);
  const int lane = threadIdx.x & 63;
  const int c4 = lane << 2;
  const float4 xrv  = ld_bf16x4(Cin + (size_t)n * 512 + 256 + c4);
  const float4 attv = *(const float4*)&att[c4];
  const int beg = rowptr[n], end = rowptr[n + 1];
  float4 acc = make_float4(0.f, 0.f, 0.f, 0.f);
  float lsum = 0.f;
  for (int p = beg; p < end; p++) {
    int src = csr_src[p];
    float4 xlv = ld_bf16x4(Cin + (size_t)src * 512 + c4);
    float4 a;
    a.x = xlv.x + xrv.x; a.y = xlv.y + xrv.y;
    a.z = xlv.z + xrv.z; a.w = xlv.w + xrv.w;
    a.x = fmaxf(a.x, 0.2f * a.x); a.y = fmaxf(a.y, 0.2f * a.y);
    a.z = fmaxf(a.z, 0.2f * a.z); a.w = fmaxf(a.w, 0.2f * a.w);
    float v = a.x * attv.x + a.y * attv.y + a.z * attv.z + a.w * attv.w;
    v += __shfl_xor(v, 1);
    v += __shfl_xor(v, 2);
    v += __shfl_xor(v, 4);
    v += __shfl_xor(v, 8);        // per-head (16-lane) logit
    float w = __expf(v);          // no-max softmax: logits O(1), safe
    lsum += w;
    acc.x += w * xlv.x; acc.y += w * xlv.y;
    acc.z += w * xlv.z; acc.w += w * xlv.w;
  }
  const float4 bv = *(const float4*)&bias[c4];
  float inv = 1.f / lsum;
  ushort4 o;
  o.x = f2bf(acc.x * inv + bv.x); o.y = f2bf(acc.y * inv + bv.y);
  o.z = f2bf(acc.z * inv + bv.z); o.w = f2bf(acc.w * inv + bv.w);
  *(ushort4*)&hout[(size_t)n * 256 + c4] = o;
}

// ============ layer 2 (H=1) + pool: 4 edges/wave via 16-lane groups ============
// Cin rows: [xl(64) | xr(64)]. Group g = lanes 16g..16g+15 handles edges beg+g, +4...
__global__ __launch_bounds__(256) void gat_gather_h1_pool(
    const ushort* __restrict__ Cin, const float* __restrict__ att,
    const float* __restrict__ bias, const int* __restrict__ rowptr,
    const int* __restrict__ csr_src, const int* __restrict__ batch,
    float* __restrict__ pooled)
{
  const int n = blockIdx.x * 4 + (threadIdx.x >> 6);
  const int lane = threadIdx.x & 63;
  const int g = lane >> 4, c4 = (lane & 15) << 2;
  const float4 xrv  = ld_bf16x4(Cin + (size_t)n * 128 + 64 + c4);
  const float4 attv = *(const float4*)&att[c4];
  const int beg = rowptr[n], end = rowptr[n + 1];
  float4 acc = make_float4(0.f, 0.f, 0.f, 0.f);
  float lsum = 0.f;
  for (int p = beg + g; p < end; p += 4) {
    int src = csr_src[p];
    float4 xlv = ld_bf16x4(Cin + (size_t)src * 128 + c4);
    float4 a;
    a.x = xlv.x + xrv.x; a.y = xlv.y + xrv.y;
    a.z = xlv.z + xrv.z; a.w = xlv.w + xrv.w;
    a.x = fmaxf(a.x, 0.2f * a.x); a.y = fmaxf(a.y, 0.2f * a.y);
    a.z = fmaxf(a.z, 0.2f * a.z); a.w = fmaxf(a.w, 0.2f * a.w);
    float v = a.x * attv.x + a.y * attv.y + a.z * attv.z + a.w * attv.w;
    v += __shfl_xor(v, 1);
    v += __shfl_xor(v, 2);
    v += __shfl_xor(v, 4);
    v += __shfl_xor(v, 8);        // 16-lane (per-edge) dot
    float w = __expf(v);
    lsum += w;
    acc.x += w * xlv.x; acc.y += w * xlv.y;
    acc.z += w * xlv.z; acc.w += w * xlv.w;
  }
  // combine the 4 edge-groups
  #pragma unroll
  for (int off = 16; off <= 32; off <<= 1) {
    lsum  += __shfl_xor(lsum, off);
    acc.x += __shfl_xor(acc.x, off); acc.y += __shfl_xor(acc.y, off);
    acc.z += __shfl_xor(acc.z, off); acc.w += __shfl_xor(acc.w, off);
  }
  if (g == 0) {
    const float4 bv = *(const float4*)&bias[c4];
    float inv = 1.f / lsum;
    int base = batch[n] * 64 + c4;
    atomicAdd(&pooled[base + 0], acc.x * inv + bv.x);
    atomicAdd(&pooled[base + 1], acc.y * inv + bv.y);
    atomicAdd(&pooled[base + 2], acc.z * inv + bv.z);
    atomicAdd(&pooled[base + 3], acc.w * inv + bv.w);
  }
}

// ============ BN (eval) + fc ============
__global__ __launch_bounds__(64) void bn_fc(
    const float* __restrict__ pooled, const float* __restrict__ gamma,
    const float* __restrict__ beta, const float* __restrict__ mean,
    const float* __restrict__ var, const float* __restrict__ fcw,
    const float* __restrict__ fcb, float* __restrict__ out)
{
  __shared__ float s[64];
  int g = blockIdx.x;
  int t = threadIdx.x;
  float p = pooled[g * 64 + t];
  s[t] = (p - mean[t]) * rsqrtf(var[t] + 1e-5f) * gamma[t] + beta[t];
  __syncthreads();
  if (t < 32) {
    float a = fcb[t];
    #pragma unroll
    for (int c = 0; c < 64; c++) a += s[c] * fcw[c * 32 + t];
    out[g * 32 + t] = a;
  }
}

extern "C" void kernel_launch(void* const* d_in, const int* in_sizes, int n_in,
                              void* d_out, int out_size, void* d_ws, size_t ws_size,
                              hipStream_t stream) {
  const float* x    = (const float*)d_in[0];
  const int*   ei   = (const int*)d_in[1];
  const int*   batch= (const int*)d_in[2];
  const float* Wl0  = (const float*)d_in[3];
  const float* Wr0  = (const float*)d_in[4];
  const float* att0 = (const float*)d_in[5];
  const float* b0   = (const float*)d_in[6];
  const float* Wl1  = (const float*)d_in[7];
  const float* Wr1  = (const float*)d_in[8];
  const float* att1 = (const float*)d_in[9];
  const float* b1   = (const float*)d_in[10];
  const float* Wl2  = (const float*)d_in[11];
  const float* Wr2  = (const float*)d_in[12];
  const float* att2 = (const float*)d_in[13];
  const float* b2   = (const float*)d_in[14];
  const float* bng  = (const float*)d_in[15];
  const float* bnb  = (const float*)d_in[16];
  const float* bnm  = (const float*)d_in[17];
  const float* bnv  = (const float*)d_in[18];
  const float* fcw  = (const float*)d_in[19];
  const float* fcb  = (const float*)d_in[20];
  float* out = (float*)d_out;

  const int* esrc = ei;
  const int* edst = ei + E_ORIG;

  // ---- workspace layout ----
  char* w = (char*)d_ws;
  ushort* x16  = (ushort*)w;                 w += (size_t)N_NODES * 128 * 2;
  ushort* Cbig = (ushort*)w;                 w += (size_t)N_NODES * 512 * 2;
  ushort* h16  = (ushort*)w;                 w += (size_t)N_NODES * 256 * 2;
  ushort* C2   = (ushort*)w;                 w += (size_t)N_NODES * 128 * 2;
  ushort* Bt01 = (ushort*)w;                 w += (size_t)512 * 256 * 2;
  ushort* Bt2  = (ushort*)w;                 w += (size_t)128 * 256 * 2;
  int* deg     = (int*)w;                    w += N_NODES * 4;
  int* rowptr  = (int*)w;                    w += (N_NODES + 1) * 4;
  int* cursor  = (int*)w;                    w += N_NODES * 4;
  int* csr_src = (int*)w;                    w += E_TOT * 4;
  float* pooled= (float*)w;

  dim3 blk(256);
  const int eblk  = (E_TOT + 255) / 256;
  const int mt    = (N_NODES + 127) / 128;   // 157

  // ---- CSR build ----
  hipMemsetAsync(deg, 0, N_NODES * 4, stream);
  deg_count<<<dim3(eblk), blk, 0, stream>>>(edst, deg);
  scan_rowptr<<<dim3(1), dim3(1024), 0, stream>>>(deg, rowptr, cursor);
  csr_fill<<<dim3(eblk), blk, 0, stream>>>(esrc, edst, cursor, csr_src);

  // ---- input cast ----
  cast_bf16<<<dim3((N_NODES * 128 / 4 + 255) / 256), blk, 0, stream>>>(
      x, x16, N_NODES * 128);

  // ---- layer 0: [xl|xr] = x @ [Wl0|Wr0] ----
  pack_wt<<<dim3((512 * 128 + 255) / 256), blk, 0, stream>>>(Wl0, Wr0, Bt01, 128, 256);
  mfma_gemm_bf16<<<dim3(mt, 4), blk, 0, stream>>>(x16, Bt01, Cbig, N_NODES, 128, 512);
  gat_gather_h4<<<dim3(N_NODES / 4), blk, 0, stream>>>(
      Cbig, att0, b0, rowptr, csr_src, h16);

  // ---- layer 1 ----
  pack_wt<<<dim3((512 * 256 + 255) / 256), blk, 0, stream>>>(Wl1, Wr1, Bt01, 256, 256);
  mfma_gemm_bf16<<<dim3(mt, 4), blk, 0, stream>>>(h16, Bt01, Cbig, N_NODES, 256, 512);
  gat_gather_h4<<<dim3(N_NODES / 4), blk, 0, stream>>>(
      Cbig, att1, b1, rowptr, csr_src, h16);

  // ---- layer 2 + pool ----
  pack_wt<<<dim3((128 * 256 + 255) / 256), blk, 0, stream>>>(Wl2, Wr2, Bt2, 256, 64);
  mfma_gemm_bf16<<<dim3(mt, 1), blk, 0, stream>>>(h16, Bt2, C2, N_NODES, 256, 128);
  hipMemsetAsync(pooled, 0, NUM_GRAPHS * 64 * 4, stream);
  gat_gather_h1_pool<<<dim3(N_NODES / 4), blk, 0, stream>>>(
      C2, att2, b2, rowptr, csr_src, batch, pooled);

  bn_fc<<<dim3(NUM_GRAPHS), dim3(64), 0, stream>>>(
      pooled, bng, bnb, bnm, bnv, fcw, fcb, out);
}

// Round 5
// 334.536 us; speedup vs baseline: 5.0598x; 1.2931x over previous
//
#include <hip/hip_runtime.h>
#include <math.h>

#define N_NODES 20000
#define E_ORIG  320000
#define E_TOT   340000
#define NUM_GRAPHS 64

typedef __attribute__((ext_vector_type(8))) short bf16x8;
typedef __attribute__((ext_vector_type(4))) float f32x4;

// fp32 -> bf16 RNE
__device__ __forceinline__ ushort f2bf(float x) {
  unsigned u = __float_as_uint(x);
  return (ushort)((u + 0x7fffu + ((u >> 16) & 1u)) >> 16);
}
// 4 consecutive bf16 -> float4 (8B load)
__device__ __forceinline__ float4 ld_bf16x4(const ushort* p) {
  ushort4 u = *(const ushort4*)p;
  float4 f;
  f.x = __uint_as_float((unsigned)u.x << 16);
  f.y = __uint_as_float((unsigned)u.y << 16);
  f.z = __uint_as_float((unsigned)u.z << 16);
  f.w = __uint_as_float((unsigned)u.w << 16);
  return f;
}
// async global->LDS, 16B per lane; lds ptr MUST be base + lane*16 in lane order
__device__ __forceinline__ void gl_lds16(const void* g, void* l) {
  __builtin_amdgcn_global_load_lds(
      (const __attribute__((address_space(1))) unsigned*)(uintptr_t)g,
      (__attribute__((address_space(3))) unsigned*)(uintptr_t)l, 16, 0, 0);
}

// ============ CSR build (by destination) ============

__global__ __launch_bounds__(256) void deg_count(
    const int* __restrict__ edst, int* __restrict__ deg)
{
  int e = blockIdx.x * 256 + threadIdx.x;
  if (e >= E_TOT) return;
  int dst = (e < E_ORIG) ? edst[e] : e - E_ORIG;
  atomicAdd(&deg[dst], 1);
}

__global__ __launch_bounds__(1024) void scan_rowptr(
    const int* __restrict__ deg, int* __restrict__ rowptr, int* __restrict__ cursor)
{
  __shared__ int part[1024];
  const int t = threadIdx.x;
  const int CH = (N_NODES + 1023) / 1024;
  int base = t * CH;
  int s = 0;
  for (int i = 0; i < CH; i++) {
    int idx = base + i;
    if (idx < N_NODES) s += deg[idx];
  }
  part[t] = s;
  __syncthreads();
  for (int off = 1; off < 1024; off <<= 1) {
    int v = (t >= off) ? part[t - off] : 0;
    __syncthreads();
    part[t] += v;
    __syncthreads();
  }
  int run = (t == 0) ? 0 : part[t - 1];
  for (int i = 0; i < CH; i++) {
    int idx = base + i;
    if (idx < N_NODES) {
      rowptr[idx] = run;
      cursor[idx] = run;
      run += deg[idx];
    }
  }
  if (t == 1023) rowptr[N_NODES] = part[1023];
}

__global__ __launch_bounds__(256) void csr_fill(
    const int* __restrict__ esrc, const int* __restrict__ edst,
    int* __restrict__ cursor, int* __restrict__ csr_src)
{
  int e = blockIdx.x * 256 + threadIdx.x;
  if (e >= E_TOT) return;
  int src, dst;
  if (e < E_ORIG) { src = esrc[e]; dst = edst[e]; }
  else            { src = dst = e - E_ORIG; }
  int pos = atomicAdd(&cursor[dst], 1);
  csr_src[pos] = src;
}

// ============ casts / weight packing ============

__global__ __launch_bounds__(256) void cast_bf16(
    const float* __restrict__ in, ushort* __restrict__ out, int n4)
{
  int i = (blockIdx.x * 256 + threadIdx.x) << 2;
  if (i >= n4) return;
  float4 v = *(const float4*)&in[i];
  ushort4 o;
  o.x = f2bf(v.x); o.y = f2bf(v.y); o.z = f2bf(v.z); o.w = f2bf(v.w);
  *(ushort4*)&out[i] = o;
}

// Bt[n][k] = (n<W ? Wl : Wr)[k][n%W], bf16.  N = 2W rows, K cols.
__global__ __launch_bounds__(256) void pack_wt(
    const float* __restrict__ Wl, const float* __restrict__ Wr,
    ushort* __restrict__ Bt, int K, int W)
{
  int idx = blockIdx.x * 256 + threadIdx.x;
  if (idx >= 2 * W * K) return;
  int n = idx / K, k = idx - n * K;
  float v = (n < W) ? Wl[(size_t)k * W + n] : Wr[(size_t)k * W + (n - W)];
  Bt[idx] = f2bf(v);
}

// ============ bf16 MFMA GEMM: C[M,N] = A[M,K] @ Bt[N,K]^T ============
__global__ __launch_bounds__(256) void mfma_gemm_bf16(
    const ushort* __restrict__ A, const ushort* __restrict__ Bt,
    ushort* __restrict__ C, int M, int K, int N)
{
  __shared__ ushort As[128 * 32];
  __shared__ ushort Bs[128 * 32];
  const int m0 = blockIdx.x * 128;
  const int n0 = blockIdx.y * 128;
  const int tid = threadIdx.x;
  const int lane = tid & 63;
  const int w = tid >> 6;
  const int wm = (w >> 1) << 6;
  const int wn = (w & 1) << 6;
  const int quad = lane >> 4;
  const int l15 = lane & 15;

  f32x4 acc[4][4] = {};

  for (int k0 = 0; k0 < K; k0 += 32) {
    #pragma unroll
    for (int r = 0; r < 2; r++) {
      int c = (r << 8) + tid;
      int row = c >> 2;
      int col = (c & 3) << 3;
      int grow = m0 + row; if (grow >= M) grow = M - 1;
      gl_lds16(A  + (size_t)grow * K + k0 + col, (char*)As + c * 16);
      gl_lds16(Bt + (size_t)(n0 + row) * K + k0 + col, (char*)Bs + c * 16);
    }
    __syncthreads();
    bf16x8 af[4], bfr[4];
    #pragma unroll
    for (int i = 0; i < 4; i++)
      af[i]  = *(const bf16x8*)&As[(wm + (i << 4) + l15) * 32 + (quad << 3)];
    #pragma unroll
    for (int j = 0; j < 4; j++)
      bfr[j] = *(const bf16x8*)&Bs[(wn + (j << 4) + l15) * 32 + (quad << 3)];
    #pragma unroll
    for (int i = 0; i < 4; i++)
      #pragma unroll
      for (int j = 0; j < 4; j++)
        acc[i][j] = __builtin_amdgcn_mfma_f32_16x16x32_bf16(
            af[i], bfr[j], acc[i][j], 0, 0, 0);
    __syncthreads();
  }

  #pragma unroll
  for (int i = 0; i < 4; i++) {
    #pragma unroll
    for (int r = 0; r < 4; r++) {
      int grow = m0 + wm + (i << 4) + (quad << 2) + r;
      if (grow >= M) continue;
      #pragma unroll
      for (int j = 0; j < 4; j++) {
        int gcol = n0 + wn + (j << 4) + l15;
        C[(size_t)grow * N + gcol] = f2bf(acc[i][j][r]);
      }
    }
  }
}

// ============ GATv2 edge phase, H=4, bf16 in/out, 2-way unrolled ============
// Cin rows: [xl(256) | xr(256)]. One wave per node; lane l = channels 4l..4l+3.
__global__ __launch_bounds__(256) void gat_gather_h4(
    const ushort* __restrict__ Cin, const float* __restrict__ att,
    const float* __restrict__ bias, const int* __restrict__ rowptr,
    const int* __restrict__ csr_src, ushort* __restrict__ hout)
{
  const int n = blockIdx.x * 4 + (threadIdx.x >> 6);
  const int lane = threadIdx.x & 63;
  const int c4 = lane << 2;
  const float4 xrv  = ld_bf16x4(Cin + (size_t)n * 512 + 256 + c4);
  const float4 attv = *(const float4*)&att[c4];
  const int beg = rowptr[n], end = rowptr[n + 1];
  float4 acc = make_float4(0.f, 0.f, 0.f, 0.f);
  float lsum = 0.f;
  int p = beg;
  for (; p + 1 < end; p += 2) {       // two independent edges per iter (ILP)
    int s0 = csr_src[p], s1 = csr_src[p + 1];
    float4 x0 = ld_bf16x4(Cin + (size_t)s0 * 512 + c4);
    float4 x1 = ld_bf16x4(Cin + (size_t)s1 * 512 + c4);
    float4 a0, a1;
    a0.x = x0.x + xrv.x; a0.y = x0.y + xrv.y; a0.z = x0.z + xrv.z; a0.w = x0.w + xrv.w;
    a1.x = x1.x + xrv.x; a1.y = x1.y + xrv.y; a1.z = x1.z + xrv.z; a1.w = x1.w + xrv.w;
    a0.x = fmaxf(a0.x, 0.2f * a0.x); a0.y = fmaxf(a0.y, 0.2f * a0.y);
    a0.z = fmaxf(a0.z, 0.2f * a0.z); a0.w = fmaxf(a0.w, 0.2f * a0.w);
    a1.x = fmaxf(a1.x, 0.2f * a1.x); a1.y = fmaxf(a1.y, 0.2f * a1.y);
    a1.z = fmaxf(a1.z, 0.2f * a1.z); a1.w = fmaxf(a1.w, 0.2f * a1.w);
    float v0 = a0.x * attv.x + a0.y * attv.y + a0.z * attv.z + a0.w * attv.w;
    float v1 = a1.x * attv.x + a1.y * attv.y + a1.z * attv.z + a1.w * attv.w;
    v0 += __shfl_xor(v0, 1); v1 += __shfl_xor(v1, 1);
    v0 += __shfl_xor(v0, 2); v1 += __shfl_xor(v1, 2);
    v0 += __shfl_xor(v0, 4); v1 += __shfl_xor(v1, 4);
    v0 += __shfl_xor(v0, 8); v1 += __shfl_xor(v1, 8);
    float w0 = __expf(v0), w1 = __expf(v1);   // no-max softmax: logits O(1)
    lsum += w0 + w1;
    acc.x += w0 * x0.x + w1 * x1.x; acc.y += w0 * x0.y + w1 * x1.y;
    acc.z += w0 * x0.z + w1 * x1.z; acc.w += w0 * x0.w + w1 * x1.w;
  }
  if (p < end) {                       // odd tail
    int s0 = csr_src[p];
    float4 x0 = ld_bf16x4(Cin + (size_t)s0 * 512 + c4);
    float4 a0;
    a0.x = x0.x + xrv.x; a0.y = x0.y + xrv.y; a0.z = x0.z + xrv.z; a0.w = x0.w + xrv.w;
    a0.x = fmaxf(a0.x, 0.2f * a0.x); a0.y = fmaxf(a0.y, 0.2f * a0.y);
    a0.z = fmaxf(a0.z, 0.2f * a0.z); a0.w = fmaxf(a0.w, 0.2f * a0.w);
    float v0 = a0.x * attv.x + a0.y * attv.y + a0.z * attv.z + a0.w * attv.w;
    v0 += __shfl_xor(v0, 1);
    v0 += __shfl_xor(v0, 2);
    v0 += __shfl_xor(v0, 4);
    v0 += __shfl_xor(v0, 8);
    float w0 = __expf(v0);
    lsum += w0;
    acc.x += w0 * x0.x; acc.y += w0 * x0.y; acc.z += w0 * x0.z; acc.w += w0 * x0.w;
  }
  const float4 bv = *(const float4*)&bias[c4];
  float inv = 1.f / lsum;
  ushort4 o;
  o.x = f2bf(acc.x * inv + bv.x); o.y = f2bf(acc.y * inv + bv.y);
  o.z = f2bf(acc.z * inv + bv.z); o.w = f2bf(acc.w * inv + bv.w);
  *(ushort4*)&hout[(size_t)n * 256 + c4] = o;
}

// ============ layer 2 (H=1): 4 edges/wave via 16-lane groups, NO atomics ====
// Cin rows: [xl(64) | xr(64)]. Writes h3[n][64] fp32 (plain stores).
__global__ __launch_bounds__(256) void gat_gather_h1(
    const ushort* __restrict__ Cin, const float* __restrict__ att,
    const float* __restrict__ bias, const int* __restrict__ rowptr,
    const int* __restrict__ csr_src, float* __restrict__ h3)
{
  const int n = blockIdx.x * 4 + (threadIdx.x >> 6);
  const int lane = threadIdx.x & 63;
  const int g = lane >> 4, c4 = (lane & 15) << 2;
  const float4 xrv  = ld_bf16x4(Cin + (size_t)n * 128 + 64 + c4);
  const float4 attv = *(const float4*)&att[c4];
  const int beg = rowptr[n], end = rowptr[n + 1];
  float4 acc = make_float4(0.f, 0.f, 0.f, 0.f);
  float lsum = 0.f;
  for (int p = beg + g; p < end; p += 4) {
    int src = csr_src[p];
    float4 xlv = ld_bf16x4(Cin + (size_t)src * 128 + c4);
    float4 a;
    a.x = xlv.x + xrv.x; a.y = xlv.y + xrv.y;
    a.z = xlv.z + xrv.z; a.w = xlv.w + xrv.w;
    a.x = fmaxf(a.x, 0.2f * a.x); a.y = fmaxf(a.y, 0.2f * a.y);
    a.z = fmaxf(a.z, 0.2f * a.z); a.w = fmaxf(a.w, 0.2f * a.w);
    float v = a.x * attv.x + a.y * attv.y + a.z * attv.z + a.w * attv.w;
    v += __shfl_xor(v, 1);
    v += __shfl_xor(v, 2);
    v += __shfl_xor(v, 4);
    v += __shfl_xor(v, 8);
    float w = __expf(v);
    lsum += w;
    acc.x += w * xlv.x; acc.y += w * xlv.y;
    acc.z += w * xlv.z; acc.w += w * xlv.w;
  }
  #pragma unroll
  for (int off = 16; off <= 32; off <<= 1) {
    lsum  += __shfl_xor(lsum, off);
    acc.x += __shfl_xor(acc.x, off); acc.y += __shfl_xor(acc.y, off);
    acc.z += __shfl_xor(acc.z, off); acc.w += __shfl_xor(acc.w, off);
  }
  if (g == 0) {
    const float4 bv = *(const float4*)&bias[c4];
    float inv = 1.f / lsum;
    float4 o;
    o.x = acc.x * inv + bv.x; o.y = acc.y * inv + bv.y;
    o.z = acc.z * inv + bv.z; o.w = acc.w * inv + bv.w;
    *(float4*)&h3[(size_t)n * 64 + c4] = o;
  }
}

// ============ fused segmented pool (batch sorted) + BN + fc ============
// One block per graph; binary-search node range; strided accumulate.
__global__ __launch_bounds__(256) void pool_bn_fc(
    const float* __restrict__ h3, const int* __restrict__ batch,
    const float* __restrict__ gamma, const float* __restrict__ beta,
    const float* __restrict__ mean, const float* __restrict__ var,
    const float* __restrict__ fcw, const float* __restrict__ fcb,
    float* __restrict__ out)
{
  __shared__ float red[256];
  __shared__ float s[64];
  const int g = blockIdx.x;
  const int t = threadIdx.x;
  const int c = t & 63, r = t >> 6;
  // lower_bound(batch, g) and lower_bound(batch, g+1)
  int lo = 0, hi = N_NODES;
  while (lo < hi) { int mid = (lo + hi) >> 1; if (batch[mid] < g) lo = mid + 1; else hi = mid; }
  int s0 = lo;
  hi = N_NODES;
  while (lo < hi) { int mid = (lo + hi) >> 1; if (batch[mid] < g + 1) lo = mid + 1; else hi = mid; }
  int e0 = lo;
  float a = 0.f;
  for (int n = s0 + r; n < e0; n += 4) a += h3[(size_t)n * 64 + c];
  red[t] = a;
  __syncthreads();
  if (r == 0) {
    float p = red[c] + red[c + 64] + red[c + 128] + red[c + 192];
    s[c] = (p - mean[c]) * rsqrtf(var[c] + 1e-5f) * gamma[c] + beta[c];
  }
  __syncthreads();
  if (t < 32) {
    float acc = fcb[t];
    #pragma unroll
    for (int k = 0; k < 64; k++) acc += s[k] * fcw[k * 32 + t];
    out[g * 32 + t] = acc;
  }
}

extern "C" void kernel_launch(void* const* d_in, const int* in_sizes, int n_in,
                              void* d_out, int out_size, void* d_ws, size_t ws_size,
                              hipStream_t stream) {
  const float* x    = (const float*)d_in[0];
  const int*   ei   = (const int*)d_in[1];
  const int*   batch= (const int*)d_in[2];
  const float* Wl0  = (const float*)d_in[3];
  const float* Wr0  = (const float*)d_in[4];
  const float* att0 = (const float*)d_in[5];
  const float* b0   = (const float*)d_in[6];
  const float* Wl1  = (const float*)d_in[7];
  const float* Wr1  = (const float*)d_in[8];
  const float* att1 = (const float*)d_in[9];
  const float* b1   = (const float*)d_in[10];
  const float* Wl2  = (const float*)d_in[11];
  const float* Wr2  = (const float*)d_in[12];
  const float* att2 = (const float*)d_in[13];
  const float* b2   = (const float*)d_in[14];
  const float* bng  = (const float*)d_in[15];
  const float* bnb  = (const float*)d_in[16];
  const float* bnm  = (const float*)d_in[17];
  const float* bnv  = (const float*)d_in[18];
  const float* fcw  = (const float*)d_in[19];
  const float* fcb  = (const float*)d_in[20];
  float* out = (float*)d_out;

  const int* esrc = ei;
  const int* edst = ei + E_ORIG;

  // ---- workspace layout ----
  char* w = (char*)d_ws;
  ushort* x16  = (ushort*)w;                 w += (size_t)N_NODES * 128 * 2;
  ushort* Cbig = (ushort*)w;                 w += (size_t)N_NODES * 512 * 2;
  ushort* h16  = (ushort*)w;                 w += (size_t)N_NODES * 256 * 2;
  ushort* C2   = (ushort*)w;                 w += (size_t)N_NODES * 128 * 2;
  float*  h3   = (float*)w;                  w += (size_t)N_NODES * 64 * 4;
  ushort* Bt01 = (ushort*)w;                 w += (size_t)512 * 256 * 2;
  ushort* Bt2  = (ushort*)w;                 w += (size_t)128 * 256 * 2;
  int* deg     = (int*)w;                    w += N_NODES * 4;
  int* rowptr  = (int*)w;                    w += (N_NODES + 1) * 4;
  int* cursor  = (int*)w;                    w += N_NODES * 4;
  int* csr_src = (int*)w;

  dim3 blk(256);
  const int eblk  = (E_TOT + 255) / 256;
  const int mt    = (N_NODES + 127) / 128;   // 157

  // ---- CSR build ----
  hipMemsetAsync(deg, 0, N_NODES * 4, stream);
  deg_count<<<dim3(eblk), blk, 0, stream>>>(edst, deg);
  scan_rowptr<<<dim3(1), dim3(1024), 0, stream>>>(deg, rowptr, cursor);
  csr_fill<<<dim3(eblk), blk, 0, stream>>>(esrc, edst, cursor, csr_src);

  // ---- input cast ----
  cast_bf16<<<dim3((N_NODES * 128 / 4 + 255) / 256), blk, 0, stream>>>(
      x, x16, N_NODES * 128);

  // ---- layer 0 ----
  pack_wt<<<dim3((512 * 128 + 255) / 256), blk, 0, stream>>>(Wl0, Wr0, Bt01, 128, 256);
  mfma_gemm_bf16<<<dim3(mt, 4), blk, 0, stream>>>(x16, Bt01, Cbig, N_NODES, 128, 512);
  gat_gather_h4<<<dim3(N_NODES / 4), blk, 0, stream>>>(
      Cbig, att0, b0, rowptr, csr_src, h16);

  // ---- layer 1 ----
  pack_wt<<<dim3((512 * 256 + 255) / 256), blk, 0, stream>>>(Wl1, Wr1, Bt01, 256, 256);
  mfma_gemm_bf16<<<dim3(mt, 4), blk, 0, stream>>>(h16, Bt01, Cbig, N_NODES, 256, 512);
  gat_gather_h4<<<dim3(N_NODES / 4), blk, 0, stream>>>(
      Cbig, att1, b1, rowptr, csr_src, h16);

  // ---- layer 2 ----
  pack_wt<<<dim3((128 * 256 + 255) / 256), blk, 0, stream>>>(Wl2, Wr2, Bt2, 256, 64);
  mfma_gemm_bf16<<<dim3(mt, 1), blk, 0, stream>>>(h16, Bt2, C2, N_NODES, 256, 128);
  gat_gather_h1<<<dim3(N_NODES / 4), blk, 0, stream>>>(
      C2, att2, b2, rowptr, csr_src, h3);

  // ---- pool + BN + fc (deterministic, batch sorted) ----
  pool_bn_fc<<<dim3(NUM_GRAPHS), blk, 0, stream>>>(
      h3, batch, bng, bnb, bnm, bnv, fcw, fcb, out);
}

// Round 6
// 324.988 us; speedup vs baseline: 5.2084x; 1.0294x over previous
//
#include <hip/hip_runtime.h>
#include <math.h>

#define N_NODES 20000
#define E_ORIG  320000
#define E_TOT   340000
#define NUM_GRAPHS 64

typedef __attribute__((ext_vector_type(8))) short bf16x8;
typedef __attribute__((ext_vector_type(4))) float f32x4;

// fp32 -> bf16 RNE
__device__ __forceinline__ ushort f2bf(float x) {
  unsigned u = __float_as_uint(x);
  return (ushort)((u + 0x7fffu + ((u >> 16) & 1u)) >> 16);
}
// 4 consecutive bf16 -> float4 (8B load)
__device__ __forceinline__ float4 ld_bf16x4(const ushort* p) {
  ushort4 u = *(const ushort4*)p;
  float4 f;
  f.x = __uint_as_float((unsigned)u.x << 16);
  f.y = __uint_as_float((unsigned)u.y << 16);
  f.z = __uint_as_float((unsigned)u.z << 16);
  f.w = __uint_as_float((unsigned)u.w << 16);
  return f;
}
// async global->LDS, 16B per lane; lds dest is wave-uniform base + lane*16
__device__ __forceinline__ void gl_lds16(const void* g, void* l) {
  __builtin_amdgcn_global_load_lds(
      (const __attribute__((address_space(1))) unsigned*)(uintptr_t)g,
      (__attribute__((address_space(3))) unsigned*)(uintptr_t)l, 16, 0, 0);
}

// ============ merged prep: cast x -> bf16, pack 3 weight pairs, zero deg ====
__global__ __launch_bounds__(256) void prep(
    const float* __restrict__ x,
    const float* __restrict__ Wl0, const float* __restrict__ Wr0,
    const float* __restrict__ Wl1, const float* __restrict__ Wr1,
    const float* __restrict__ Wl2, const float* __restrict__ Wr2,
    ushort* __restrict__ x16, ushort* __restrict__ Bt0,
    ushort* __restrict__ Bt1, ushort* __restrict__ Bt2, int* __restrict__ deg)
{
  const int Z0 = 640000;           // x cast, float4 granules (20000*128/4)
  const int Z1 = Z0 + 65536;       // Bt0: 512(n) x 128(k)
  const int Z2 = Z1 + 131072;      // Bt1: 512 x 256
  const int Z3 = Z2 + 32768;       // Bt2: 128 x 256
  const int Z4 = Z3 + 5000;       // deg zero, int4 granules
  int t = blockIdx.x * 256 + threadIdx.x;
  if (t < Z0) {
    int i = t << 2;
    float4 v = *(const float4*)&x[i];
    ushort4 o; o.x = f2bf(v.x); o.y = f2bf(v.y); o.z = f2bf(v.z); o.w = f2bf(v.w);
    *(ushort4*)&x16[i] = o;
  } else if (t < Z1) {
    int idx = t - Z0; int n = idx >> 7, k = idx & 127;
    float v = (n < 256) ? Wl0[k * 256 + n] : Wr0[k * 256 + (n - 256)];
    Bt0[idx] = f2bf(v);
  } else if (t < Z2) {
    int idx = t - Z1; int n = idx >> 8, k = idx & 255;
    float v = (n < 256) ? Wl1[k * 256 + n] : Wr1[k * 256 + (n - 256)];
    Bt1[idx] = f2bf(v);
  } else if (t < Z3) {
    int idx = t - Z2; int n = idx >> 8, k = idx & 255;
    float v = (n < 64) ? Wl2[k * 64 + n] : Wr2[k * 64 + (n - 64)];
    Bt2[idx] = f2bf(v);
  } else if (t < Z4) {
    int4 z = {0, 0, 0, 0};
    *(int4*)&deg[(t - Z3) << 2] = z;
  }
}

// ============ CSR build (by destination) ============

__global__ __launch_bounds__(256) void deg_count(
    const int* __restrict__ edst, int* __restrict__ deg)
{
  int e = blockIdx.x * 256 + threadIdx.x;
  if (e >= E_TOT) return;
  int dst = (e < E_ORIG) ? edst[e] : e - E_ORIG;
  atomicAdd(&deg[dst], 1);
}

__global__ __launch_bounds__(1024) void scan_rowptr(
    const int* __restrict__ deg, int* __restrict__ rowptr, int* __restrict__ cursor)
{
  __shared__ int part[1024];
  const int t = threadIdx.x;
  const int CH = (N_NODES + 1023) / 1024;
  int base = t * CH;
  int s = 0;
  for (int i = 0; i < CH; i++) {
    int idx = base + i;
    if (idx < N_NODES) s += deg[idx];
  }
  part[t] = s;
  __syncthreads();
  for (int off = 1; off < 1024; off <<= 1) {
    int v = (t >= off) ? part[t - off] : 0;
    __syncthreads();
    part[t] += v;
    __syncthreads();
  }
  int run = (t == 0) ? 0 : part[t - 1];
  for (int i = 0; i < CH; i++) {
    int idx = base + i;
    if (idx < N_NODES) {
      rowptr[idx] = run;
      cursor[idx] = run;
      run += deg[idx];
    }
  }
  if (t == 1023) rowptr[N_NODES] = part[1023];
}

__global__ __launch_bounds__(256) void csr_fill(
    const int* __restrict__ esrc, const int* __restrict__ edst,
    int* __restrict__ cursor, int* __restrict__ csr_src)
{
  int e = blockIdx.x * 256 + threadIdx.x;
  if (e >= E_TOT) return;
  int src, dst;
  if (e < E_ORIG) { src = esrc[e]; dst = edst[e]; }
  else            { src = dst = e - E_ORIG; }
  int pos = atomicAdd(&cursor[dst], 1);
  csr_src[pos] = src;
}

// ============ bf16 MFMA GEMM: C[M,N] = A[M,K] @ Bt[N,K]^T ============
// BK=64, 128x128 tile, 4 waves x (4x4 16x16x32 MFMAs x 2 ksteps)/iter.
// XCD-swizzled: xcd=bid&7 keeps the same m-slice on one XCD across n-passes.
// Epilogue: wave-private LDS repack (stride 72) -> 16B coalesced stores.
// grid: 160 * (N/128) blocks. K%64==0, N%128==0.
__global__ __launch_bounds__(256) void mfma_gemm_bf16(
    const ushort* __restrict__ A, const ushort* __restrict__ Bt,
    ushort* __restrict__ C, int M, int K, int N)
{
  __shared__ char smem[36864];          // staging 32KB | repack 4x9216B
  ushort* As = (ushort*)smem;           // [128][64]
  ushort* Bs = As + 8192;               // [128][64]

  const int mtiles = (M + 127) >> 7;
  const int bid = blockIdx.x;
  const int xcd = bid & 7;
  const int i = bid >> 3;
  const int n0 = (i / 20) << 7;
  const int m = xcd + ((i % 20) << 3);
  if (m >= mtiles) return;
  const int m0 = m << 7;

  const int tid = threadIdx.x;
  const int lane = tid & 63;
  const int w = tid >> 6;
  const int wm = (w >> 1) << 6;
  const int wn = (w & 1) << 6;
  const int quad = lane >> 4;
  const int l15 = lane & 15;

  f32x4 acc[4][4] = {};

  for (int k0 = 0; k0 < K; k0 += 64) {
    #pragma unroll
    for (int r = 0; r < 4; r++) {
      int c = (r << 8) + tid;           // chunk 0..1023
      int row = c >> 3;                 // 0..127
      int col = (c & 7) << 3;           // ushort col 0..56
      int ga = m0 + row; if (ga >= M) ga = M - 1;
      gl_lds16(A  + (size_t)ga * K + k0 + col, (char*)As + c * 16);
      gl_lds16(Bt + (size_t)(n0 + row) * K + k0 + col, (char*)Bs + c * 16);
    }
    __syncthreads();
    #pragma unroll
    for (int ks = 0; ks < 2; ks++) {
      bf16x8 af[4], bfr[4];
      #pragma unroll
      for (int ii = 0; ii < 4; ii++)
        af[ii]  = *(const bf16x8*)&As[(wm + (ii << 4) + l15) * 64 + (ks << 5) + (quad << 3)];
      #pragma unroll
      for (int j = 0; j < 4; j++)
        bfr[j] = *(const bf16x8*)&Bs[(wn + (j << 4) + l15) * 64 + (ks << 5) + (quad << 3)];
      #pragma unroll
      for (int ii = 0; ii < 4; ii++)
        #pragma unroll
        for (int j = 0; j < 4; j++)
          acc[ii][j] = __builtin_amdgcn_mfma_f32_16x16x32_bf16(
              af[ii], bfr[j], acc[ii][j], 0, 0, 0);
    }
    __syncthreads();                    // all reads done before next stage/repack
  }

  // epilogue: wave-private repack (64 rows x stride 72 ushorts = 9216B/wave)
  ushort* Cs = (ushort*)smem + w * 4608;
  #pragma unroll
  for (int ii = 0; ii < 4; ii++)
    #pragma unroll
    for (int j = 0; j < 4; j++)
      #pragma unroll
      for (int r = 0; r < 4; r++)
        Cs[((ii << 4) + (quad << 2) + r) * 72 + (j << 4) + l15] = f2bf(acc[ii][j][r]);
  #pragma unroll
  for (int it = 0; it < 8; it++) {
    int row = (it << 3) + (lane >> 3);  // 0..63
    int cc = lane & 7;
    bf16x8 v = *(const bf16x8*)&Cs[row * 72 + (cc << 3)];
    int grow = m0 + wm + row;
    if (grow < M)
      *(bf16x8*)&C[(size_t)grow * N + n0 + wn + (cc << 3)] = v;
  }
}

// ============ GATv2 edge phase, H=4, bf16, 4-wide unrolled ============
// Cin rows: [xl(256) | xr(256)]. One wave per node; lane l = channels 4l..4l+3.
__device__ __forceinline__ void h4_term(
    float4 xlv, const float4& xrv, const float4& attv, float& v)
{
  float4 a;
  a.x = xlv.x + xrv.x; a.y = xlv.y + xrv.y;
  a.z = xlv.z + xrv.z; a.w = xlv.w + xrv.w;
  a.x = fmaxf(a.x, 0.2f * a.x); a.y = fmaxf(a.y, 0.2f * a.y);
  a.z = fmaxf(a.z, 0.2f * a.z); a.w = fmaxf(a.w, 0.2f * a.w);
  v = a.x * attv.x + a.y * attv.y + a.z * attv.z + a.w * attv.w;
}

__global__ __launch_bounds__(256) void gat_gather_h4(
    const ushort* __restrict__ Cin, const float* __restrict__ att,
    const float* __restrict__ bias, const int* __restrict__ rowptr,
    const int* __restrict__ csr_src, ushort* __restrict__ hout)
{
  const int n = blockIdx.x * 4 + (threadIdx.x >> 6);
  const int lane = threadIdx.x & 63;
  const int c4 = lane << 2;
  const float4 xrv  = ld_bf16x4(Cin + (size_t)n * 512 + 256 + c4);
  const float4 attv = *(const float4*)&att[c4];
  const int beg = rowptr[n], end = rowptr[n + 1];
  float4 acc = make_float4(0.f, 0.f, 0.f, 0.f);
  float lsum = 0.f;
  int p = beg;
  for (; p + 3 < end; p += 4) {         // 4 independent edges in flight
    int s0 = csr_src[p],     s1 = csr_src[p + 1];
    int s2 = csr_src[p + 2], s3 = csr_src[p + 3];
    float4 x0 = ld_bf16x4(Cin + (size_t)s0 * 512 + c4);
    float4 x1 = ld_bf16x4(Cin + (size_t)s1 * 512 + c4);
    float4 x2 = ld_bf16x4(Cin + (size_t)s2 * 512 + c4);
    float4 x3 = ld_bf16x4(Cin + (size_t)s3 * 512 + c4);
    float v0, v1, v2, v3;
    h4_term(x0, xrv, attv, v0); h4_term(x1, xrv, attv, v1);
    h4_term(x2, xrv, attv, v2); h4_term(x3, xrv, attv, v3);
    v0 += __shfl_xor(v0, 1); v1 += __shfl_xor(v1, 1);
    v2 += __shfl_xor(v2, 1); v3 += __shfl_xor(v3, 1);
    v0 += __shfl_xor(v0, 2); v1 += __shfl_xor(v1, 2);
    v2 += __shfl_xor(v2, 2); v3 += __shfl_xor(v3, 2);
    v0 += __shfl_xor(v0, 4); v1 += __shfl_xor(v1, 4);
    v2 += __shfl_xor(v2, 4); v3 += __shfl_xor(v3, 4);
    v0 += __shfl_xor(v0, 8); v1 += __shfl_xor(v1, 8);
    v2 += __shfl_xor(v2, 8); v3 += __shfl_xor(v3, 8);
    float w0 = __expf(v0), w1 = __expf(v1);    // no-max softmax: logits O(1)
    float w2 = __expf(v2), w3 = __expf(v3);
    lsum += (w0 + w1) + (w2 + w3);
    acc.x += w0 * x0.x + w1 * x1.x + w2 * x2.x + w3 * x3.x;
    acc.y += w0 * x0.y + w1 * x1.y + w2 * x2.y + w3 * x3.y;
    acc.z += w0 * x0.z + w1 * x1.z + w2 * x2.z + w3 * x3.z;
    acc.w += w0 * x0.w + w1 * x1.w + w2 * x2.w + w3 * x3.w;
  }
  for (; p < end; p++) {
    int s0 = csr_src[p];
    float4 x0 = ld_bf16x4(Cin + (size_t)s0 * 512 + c4);
    float v0;
    h4_term(x0, xrv, attv, v0);
    v0 += __shfl_xor(v0, 1);
    v0 += __shfl_xor(v0, 2);
    v0 += __shfl_xor(v0, 4);
    v0 += __shfl_xor(v0, 8);
    float w0 = __expf(v0);
    lsum += w0;
    acc.x += w0 * x0.x; acc.y += w0 * x0.y; acc.z += w0 * x0.z; acc.w += w0 * x0.w;
  }
  const float4 bv = *(const float4*)&bias[c4];
  float inv = 1.f / lsum;
  ushort4 o;
  o.x = f2bf(acc.x * inv + bv.x); o.y = f2bf(acc.y * inv + bv.y);
  o.z = f2bf(acc.z * inv + bv.z); o.w = f2bf(acc.w * inv + bv.w);
  *(ushort4*)&hout[(size_t)n * 256 + c4] = o;
}

// ============ layer 2 (H=1): 4 edges/wave via 16-lane groups, no atomics ====
__global__ __launch_bounds__(256) void gat_gather_h1(
    const ushort* __restrict__ Cin, const float* __restrict__ att,
    const float* __restrict__ bias, const int* __restrict__ rowptr,
    const int* __restrict__ csr_src, float* __restrict__ h3)
{
  const int n = blockIdx.x * 4 + (threadIdx.x >> 6);
  const int lane = threadIdx.x & 63;
  const int g = lane >> 4, c4 = (lane & 15) << 2;
  const float4 xrv  = ld_bf16x4(Cin + (size_t)n * 128 + 64 + c4);
  const float4 attv = *(const float4*)&att[c4];
  const int beg = rowptr[n], end = rowptr[n + 1];
  float4 acc = make_float4(0.f, 0.f, 0.f, 0.f);
  float lsum = 0.f;
  for (int p = beg + g; p < end; p += 4) {
    int src = csr_src[p];
    float4 xlv = ld_bf16x4(Cin + (size_t)src * 128 + c4);
    float v;
    h4_term(xlv, xrv, attv, v);
    v += __shfl_xor(v, 1);
    v += __shfl_xor(v, 2);
    v += __shfl_xor(v, 4);
    v += __shfl_xor(v, 8);
    float w = __expf(v);
    lsum += w;
    acc.x += w * xlv.x; acc.y += w * xlv.y;
    acc.z += w * xlv.z; acc.w += w * xlv.w;
  }
  #pragma unroll
  for (int off = 16; off <= 32; off <<= 1) {
    lsum  += __shfl_xor(lsum, off);
    acc.x += __shfl_xor(acc.x, off); acc.y += __shfl_xor(acc.y, off);
    acc.z += __shfl_xor(acc.z, off); acc.w += __shfl_xor(acc.w, off);
  }
  if (g == 0) {
    const float4 bv = *(const float4*)&bias[c4];
    float inv = 1.f / lsum;
    float4 o;
    o.x = acc.x * inv + bv.x; o.y = acc.y * inv + bv.y;
    o.z = acc.z * inv + bv.z; o.w = acc.w * inv + bv.w;
    *(float4*)&h3[(size_t)n * 64 + c4] = o;
  }
}

// ============ fused segmented pool (batch sorted) + BN + fc ============
__global__ __launch_bounds__(256) void pool_bn_fc(
    const float* __restrict__ h3, const int* __restrict__ batch,
    const float* __restrict__ gamma, const float* __restrict__ beta,
    const float* __restrict__ mean, const float* __restrict__ var,
    const float* __restrict__ fcw, const float* __restrict__ fcb,
    float* __restrict__ out)
{
  __shared__ float red[256];
  __shared__ float s[64];
  const int g = blockIdx.x;
  const int t = threadIdx.x;
  const int c = t & 63, r = t >> 6;
  int lo = 0, hi = N_NODES;
  while (lo < hi) { int mid = (lo + hi) >> 1; if (batch[mid] < g) lo = mid + 1; else hi = mid; }
  int s0 = lo;
  hi = N_NODES;
  while (lo < hi) { int mid = (lo + hi) >> 1; if (batch[mid] < g + 1) lo = mid + 1; else hi = mid; }
  int e0 = lo;
  float a = 0.f;
  for (int n = s0 + r; n < e0; n += 4) a += h3[(size_t)n * 64 + c];
  red[t] = a;
  __syncthreads();
  if (r == 0) {
    float p = red[c] + red[c + 64] + red[c + 128] + red[c + 192];
    s[c] = (p - mean[c]) * rsqrtf(var[c] + 1e-5f) * gamma[c] + beta[c];
  }
  __syncthreads();
  if (t < 32) {
    float acc = fcb[t];
    #pragma unroll
    for (int k = 0; k < 64; k++) acc += s[k] * fcw[k * 32 + t];
    out[g * 32 + t] = acc;
  }
}

extern "C" void kernel_launch(void* const* d_in, const int* in_sizes, int n_in,
                              void* d_out, int out_size, void* d_ws, size_t ws_size,
                              hipStream_t stream) {
  const float* x    = (const float*)d_in[0];
  const int*   ei   = (const int*)d_in[1];
  const int*   batch= (const int*)d_in[2];
  const float* Wl0  = (const float*)d_in[3];
  const float* Wr0  = (const float*)d_in[4];
  const float* att0 = (const float*)d_in[5];
  const float* b0   = (const float*)d_in[6];
  const float* Wl1  = (const float*)d_in[7];
  const float* Wr1  = (const float*)d_in[8];
  const float* att1 = (const float*)d_in[9];
  const float* b1   = (const float*)d_in[10];
  const float* Wl2  = (const float*)d_in[11];
  const float* Wr2  = (const float*)d_in[12];
  const float* att2 = (const float*)d_in[13];
  const float* b2   = (const float*)d_in[14];
  const float* bng  = (const float*)d_in[15];
  const float* bnb  = (const float*)d_in[16];
  const float* bnm  = (const float*)d_in[17];
  const float* bnv  = (const float*)d_in[18];
  const float* fcw  = (const float*)d_in[19];
  const float* fcb  = (const float*)d_in[20];
  float* out = (float*)d_out;

  const int* esrc = ei;
  const int* edst = ei + E_ORIG;

  // ---- workspace layout ----
  char* w = (char*)d_ws;
  ushort* x16  = (ushort*)w;                 w += (size_t)N_NODES * 128 * 2;
  ushort* Cbig = (ushort*)w;                 w += (size_t)N_NODES * 512 * 2;
  ushort* h16  = (ushort*)w;                 w += (size_t)N_NODES * 256 * 2;
  ushort* C2   = (ushort*)w;                 w += (size_t)N_NODES * 128 * 2;
  float*  h3   = (float*)w;                  w += (size_t)N_NODES * 64 * 4;
  ushort* Bt0  = (ushort*)w;                 w += (size_t)512 * 128 * 2;
  ushort* Bt1  = (ushort*)w;                 w += (size_t)512 * 256 * 2;
  ushort* Bt2  = (ushort*)w;                 w += (size_t)128 * 256 * 2;
  int* deg     = (int*)w;                    w += N_NODES * 4;
  int* rowptr  = (int*)w;                    w += (N_NODES + 1) * 4;
  int* cursor  = (int*)w;                    w += N_NODES * 4;
  int* csr_src = (int*)w;

  dim3 blk(256);
  const int eblk = (E_TOT + 255) / 256;

  // ---- prep: cast + pack all weights + zero deg (one launch) ----
  prep<<<dim3(3416), blk, 0, stream>>>(
      x, Wl0, Wr0, Wl1, Wr1, Wl2, Wr2, x16, Bt0, Bt1, Bt2, deg);

  // ---- CSR build ----
  deg_count<<<dim3(eblk), blk, 0, stream>>>(edst, deg);
  scan_rowptr<<<dim3(1), dim3(1024), 0, stream>>>(deg, rowptr, cursor);
  csr_fill<<<dim3(eblk), blk, 0, stream>>>(esrc, edst, cursor, csr_src);

  // ---- layer 0 ----
  mfma_gemm_bf16<<<dim3(160 * 4), blk, 0, stream>>>(x16, Bt0, Cbig, N_NODES, 128, 512);
  gat_gather_h4<<<dim3(N_NODES / 4), blk, 0, stream>>>(
      Cbig, att0, b0, rowptr, csr_src, h16);

  // ---- layer 1 ----
  mfma_gemm_bf16<<<dim3(160 * 4), blk, 0, stream>>>(h16, Bt1, Cbig, N_NODES, 256, 512);
  gat_gather_h4<<<dim3(N_NODES / 4), blk, 0, stream>>>(
      Cbig, att1, b1, rowptr, csr_src, h16);

  // ---- layer 2 ----
  mfma_gemm_bf16<<<dim3(160 * 1), blk, 0, stream>>>(h16, Bt2, C2, N_NODES, 256, 128);
  gat_gather_h1<<<dim3(N_NODES / 4), blk, 0, stream>>>(
      C2, att2, b2, rowptr, csr_src, h3);

  // ---- pool + BN + fc ----
  pool_bn_fc<<<dim3(NUM_GRAPHS), blk, 0, stream>>>(
      h3, batch, bng, bnb, bnm, bnv, fcw, fcb, out);
}